// Round 11
// baseline (176.192 us; speedup 1.0000x reference)
//
#include <hip/hip_runtime.h>

#define DIM 4096
using F2 = float2;

// R11: R9 machinery (verified: layouts, swizzles, gates, 5-phase schedule) with
// TWO batch states per block, software-pipelined through one 32 KB LDS buffer.
// Grid 1024 = 4 blocks/CU -> whole grid co-resident; each transpose of state k
// is padded with register-resident gate passes of the other state, hiding the
// LDS drain in-stream. Gate order per state is byte-identical to R9.
// Layout A: reg = a[11:7], qubits {0,1,2,3,4} masks {16,8,4,2,1}; t = a[6:0]
// Layout B: reg = a[7:3],  qubits {4,5,6,7,8} masks {16,8,4,2,1}; t = {a[11:8],a[2:0]}
// Layout C: reg = {a[3:0],a[11]}, qubits {8,9,10,11,0} masks {16,8,4,2,1}; t = a[10:4]

__device__ __forceinline__ int addrA(int r, int t) { return (r << 7) | t; }
__device__ __forceinline__ int addrB(int r, int t) { return ((t >> 3) << 8) | (r << 3) | (t & 7); }
__device__ __forceinline__ int addrC(int r, int t) { return ((r & 1) << 11) | (t << 4) | (r >> 1); }
__device__ __forceinline__ int swzAB(int a) { return a ^ ((a >> 5) & 8); }
__device__ __forceinline__ int swzBC(int a) { return a ^ ((a >> 4) & 15) ^ ((a >> 5) & 8); }

// ---- packed fp32 complex primitives (VOP3P) — proven R8/R9 ----
__device__ __forceinline__ F2 pk_mul_bl(F2 a, F2 u) {   // (a.x*u.x, a.y*u.x)
    F2 d;
    asm("v_pk_mul_f32 %0, %1, %2 op_sel:[0,0] op_sel_hi:[1,0]"
        : "=v"(d) : "v"(a), "v"(u));
    return d;
}
__device__ __forceinline__ void pk_cross(F2& d, F2 a, F2 u) {  // d += (-a.y*u.y, a.x*u.y)
    asm("v_pk_fma_f32 %0, %1, %2, %0 op_sel:[1,1,0] op_sel_hi:[0,1,1] neg_lo:[1,0,0]"
        : "+v"(d) : "v"(a), "v"(u));
}
__device__ __forceinline__ void pk_fma_bl(F2& d, F2 a, F2 u) { // d += (a.x*u.x, a.y*u.x)
    asm("v_pk_fma_f32 %0, %1, %2, %0 op_sel:[0,0,0] op_sel_hi:[1,0,1]"
        : "+v"(d) : "v"(a), "v"(u));
}
__device__ __forceinline__ void pk_swapneg(F2& d, F2 a, F2 cs) { // d += (a.y*cs.y, -a.x*cs.y)
    asm("v_pk_fma_f32 %0, %1, %2, %0 op_sel:[1,1,0] op_sel_hi:[0,1,1] neg_hi:[1,0,0]"
        : "+v"(d) : "v"(a), "v"(cs));
}
__device__ __forceinline__ void pk_fma(F2& d, F2 a, F2 b) {    // d += a*b
    asm("v_pk_fma_f32 %0, %1, %2, %0" : "+v"(d) : "v"(a), "v"(b));
}
__device__ __forceinline__ void pk_imacc(F2& d, F2 a0, F2 a1) { // d += (a0.x*a1.y, -a0.y*a1.x)
    asm("v_pk_fma_f32 %0, %1, %2, %0 op_sel:[0,1,0] op_sel_hi:[1,0,1] neg_hi:[1,0,0]"
        : "+v"(d) : "v"(a0), "v"(a1));
}
__device__ __forceinline__ F2 pk_cmul(F2 u, F2 a) {
    F2 d = pk_mul_bl(a, u);
    pk_cross(d, a, u);
    return d;
}
__device__ __forceinline__ void pk_cfma(F2& d, F2 u, F2 a) {
    pk_fma_bl(d, a, u);
    pk_cross(d, a, u);
}

__device__ __forceinline__ void build_u(float tx, float ty, float tz, float* u) {
    float sx = sinf(0.5f*tx), cx = cosf(0.5f*tx);
    float sy = sinf(0.5f*ty), cy = cosf(0.5f*ty);
    float sz = sinf(0.5f*tz), cz = cosf(0.5f*tz);
    float A00r = cy*cx, A00i =  sy*sx;     // A = Ry*Rx
    float A01r = -sy*cx, A01i = -cy*sx;
    float A10r =  sy*cx, A10i = -cy*sx;
    float A11r =  cy*cx, A11i = -sy*sx;
    // U = Rz*A: row0 *= (cz - i sz), row1 *= (cz + i sz)   [verified r1/3/5..9]
    u[0] = cz*A00r + sz*A00i;  u[1] = cz*A00i - sz*A00r;
    u[2] = cz*A01r + sz*A01i;  u[3] = cz*A01i - sz*A01r;
    u[4] = cz*A10r - sz*A10i;  u[5] = cz*A10i + sz*A10r;
    u[6] = cz*A11r - sz*A11i;  u[7] = cz*A11i + sz*A11r;
}

// coef layout (floats): [0..95] U0 plain (q*8); [96..191] RX(ang[36+q-1])*U0[q] (q=1..11);
// [192..287] U1 plain; [288..295] U1[0]*RX(ang[47]); [296..319] L1 CRX (cos,sin)[c=0..11]
__global__ void prep_kernel(const float* __restrict__ ang, float* __restrict__ coef) {
    int t = threadIdx.x;
    if (t < 12) {
        float u[8]; build_u(ang[t], ang[12+t], ang[24+t], u);
#pragma unroll
        for (int j = 0; j < 8; ++j) coef[t*8 + j] = u[j];
    } else if (t < 24) {
        int q = t - 12;
        float u[8]; build_u(ang[48+q], ang[60+q], ang[72+q], u);
#pragma unroll
        for (int j = 0; j < 8; ++j) coef[192 + q*8 + j] = u[j];
    } else if (t < 36) {
        int c = t - 24;
        float th = 0.5f * ang[95 - c];     // L1 ring gate (c,c+1) = tape slot 84+(11-c)
        coef[296 + c*2]     = cosf(th);
        coef[296 + c*2 + 1] = sinf(th);
    } else if (t < 47) {
        int q = t - 35;                    // 1..11: M = RX(ang[36+q-1]) * U0[q]
        float u[8]; build_u(ang[q], ang[12+q], ang[24+q], u);
        float c = cosf(0.5f*ang[36+q-1]), s = sinf(0.5f*ang[36+q-1]);
        float m[8];
        m[0] = c*u[0] + s*u[5];  m[1] = c*u[1] - s*u[4];   // M00 = c u00 - i s u10
        m[2] = c*u[2] + s*u[7];  m[3] = c*u[3] - s*u[6];   // M01 = c u01 - i s u11
        m[4] = s*u[1] + c*u[4];  m[5] = -s*u[0] + c*u[5];  // M10 = -i s u00 + c u10
        m[6] = s*u[3] + c*u[6];  m[7] = -s*u[2] + c*u[7];  // M11 = -i s u01 + c u11
#pragma unroll
        for (int j = 0; j < 8; ++j) coef[96 + q*8 + j] = m[j];
    } else if (t == 47) {                  // M = U1[0] * RX(ang[47])  [CR0(11,0) then U1(0)]
        float u[8]; build_u(ang[48], ang[60], ang[72], u);
        float c = cosf(0.5f*ang[47]), s = sinf(0.5f*ang[47]);
        float m[8];
        m[0] = c*u[0] + s*u[3];  m[1] = c*u[1] - s*u[2];   // M00 = c u00 - i s u01
        m[2] = s*u[1] + c*u[2];  m[3] = -s*u[0] + c*u[3];  // M01 = -i s u00 + c u01
        m[4] = c*u[4] + s*u[7];  m[5] = c*u[5] - s*u[6];   // M10 = c u10 - i s u11
        m[6] = s*u[5] + c*u[6];  m[7] = -s*u[4] + c*u[7];  // M11 = -i s u10 + c u11
#pragma unroll
        for (int j = 0; j < 8; ++j) coef[288 + j] = m[j];
    }
}

template<int M>
__device__ __forceinline__ void g1q(F2* amp, const float* __restrict__ u) {
    F2 u00 = {u[0], u[1]}, u01 = {u[2], u[3]};
    F2 u10 = {u[4], u[5]}, u11 = {u[6], u[7]};
#pragma unroll
    for (int r0 = 0; r0 < 32; ++r0) {
        if (r0 & M) continue;
        const int r1 = r0 + M;
        F2 a0 = amp[r0], a1 = amp[r1];
        F2 n0 = pk_cmul(u00, a0); pk_cfma(n0, u01, a1);
        F2 n1 = pk_cmul(u10, a0); pk_cfma(n1, u11, a1);
        amp[r0] = n0; amp[r1] = n1;
    }
}

template<int MSEL, int M>   // matrix selected by compile-time control reg bit MSEL
__device__ __forceinline__ void fg1q(F2* amp, const float* __restrict__ uA,
                                     const float* __restrict__ uB) {
    F2 a00 = {uA[0], uA[1]}, a01 = {uA[2], uA[3]}, a10 = {uA[4], uA[5]}, a11 = {uA[6], uA[7]};
    F2 b00 = {uB[0], uB[1]}, b01 = {uB[2], uB[3]}, b10 = {uB[4], uB[5]}, b11 = {uB[6], uB[7]};
#pragma unroll
    for (int r0 = 0; r0 < 32; ++r0) {
        if (r0 & M) continue;
        const int r1 = r0 + M;
        const bool sel = (r0 & MSEL) != 0;           // compile-time
        F2 u00 = sel ? b00 : a00, u01 = sel ? b01 : a01;
        F2 u10 = sel ? b10 : a10, u11 = sel ? b11 : a11;
        F2 a0 = amp[r0], a1 = amp[r1];
        F2 n0 = pk_cmul(u00, a0); pk_cfma(n0, u01, a1);
        F2 n1 = pk_cmul(u10, a0); pk_cfma(n1, u11, a1);
        amp[r0] = n0; amp[r1] = n1;
    }
}

template<int MC, int MT>
__device__ __forceinline__ void crx(F2* amp, F2 cs) {
#pragma unroll
    for (int r0 = 0; r0 < 32; ++r0) {
        if (!(r0 & MC) || (r0 & MT)) continue;
        const int r1 = r0 + MT;
        F2 a0 = amp[r0], a1 = amp[r1];
        F2 n0 = pk_mul_bl(a0, cs); pk_swapneg(n0, a1, cs);
        F2 n1 = pk_mul_bl(a1, cs); pk_swapneg(n1, a0, cs);
        amp[r0] = n0; amp[r1] = n1;
    }
}

template<int M>
__device__ __forceinline__ void expv(const F2* amp, int q, int lane,
                                     float& fx, float& fy, float& fz) {
    F2 zp = {0.f, 0.f}, zm = {0.f, 0.f}, xp = {0.f, 0.f}, ip = {0.f, 0.f};
#pragma unroll
    for (int r0 = 0; r0 < 32; ++r0) {
        if (r0 & M) continue;
        const int r1 = r0 + M;
        F2 a0 = amp[r0], a1 = amp[r1];
        pk_fma(zp, a0, a0);
        pk_fma(zm, a1, a1);
        pk_fma(xp, a0, a1);
        pk_imacc(ip, a0, a1);
    }
    float zz = (zp.x + zp.y) - (zm.x + zm.y);
    float xr = 2.f * (xp.x + xp.y);
    float xi = 2.f * (ip.x + ip.y);
#pragma unroll
    for (int off = 32; off; off >>= 1) {
        xr += __shfl_xor(xr, off);
        xi += __shfl_xor(xi, off);
        zz += __shfl_xor(zz, off);
    }
    if (lane == q) { fx = xr; fy = xi; fz = zz; }
}

#define ST(A, ADDR, SWZ) \
  { _Pragma("unroll") for (int r = 0; r < 32; ++r) psi[SWZ(ADDR(r, t))] = A[r]; }
#define LDR(A, ADDR, SWZ) \
  { _Pragma("unroll") for (int r = 0; r < 32; ++r) A[r] = psi[SWZ(ADDR(r, t))]; }

#define U0P(A, q, M)        g1q<M>(A, cf + (q)*8)
#define FU0(A, q, MS, M)    fg1q<MS, M>(A, cf + (q)*8, cf + 96 + (q)*8)
#define U1P(A, q, M)        g1q<M>(A, cf + 192 + (q)*8)
#define CR1(A, c, MC, MT)   crx<MC, MT>(A, F2{cf[296 + (c)*2], cf[296 + (c)*2 + 1]})
#define EXPV(A, q, M, FX, FY, FZ)  expv<M>(A, q, lane, FX, FY, FZ)

// ---- R9's verified per-phase gate groups, split for pipelining ----
#define GA(A)        { U0P(A,0,16); FU0(A,1,16,8); FU0(A,2,8,4); FU0(A,3,4,2); FU0(A,4,2,1); }
#define GB_1(A)      { FU0(A,5,16,8); FU0(A,6,8,4); }
#define GB_2(A)      { FU0(A,7,4,2); FU0(A,8,2,1); }
#define GC_1(A)      { FU0(A,9,16,8); FU0(A,10,8,4); FU0(A,11,4,2); \
                       fg1q<2,1>(A, cf + 192, cf + 288); U1P(A,8,16); }
#define GC_2(A,FX,FY,FZ) { U1P(A,9,8); U1P(A,10,4); U1P(A,11,2); \
                       CR1(A,11,2,1); CR1(A,10,4,2); CR1(A,9,8,4); CR1(A,8,16,8); \
                       EXPV(A,9,8,FX,FY,FZ); EXPV(A,10,4,FX,FY,FZ); EXPV(A,11,2,FX,FY,FZ); }
#define GBP_1(A)     { U1P(A,4,16); U1P(A,5,8); }
#define GBP_2(A,FX,FY,FZ) { U1P(A,6,4); U1P(A,7,2); \
                       CR1(A,7,2,1); CR1(A,6,4,2); CR1(A,5,8,4); CR1(A,4,16,8); \
                       EXPV(A,5,8,FX,FY,FZ); EXPV(A,6,4,FX,FY,FZ); \
                       EXPV(A,7,2,FX,FY,FZ); EXPV(A,8,1,FX,FY,FZ); }
#define GAP_1(A)     { U1P(A,1,8); U1P(A,2,4); }
#define GAP_2(A,FX,FY,FZ) { U1P(A,3,2); \
                       CR1(A,3,2,1); CR1(A,2,4,2); CR1(A,1,8,4); CR1(A,0,16,8); \
                       EXPV(A,0,16,FX,FY,FZ); EXPV(A,1,8,FX,FY,FZ); EXPV(A,2,4,FX,FY,FZ); \
                       EXPV(A,3,2,FX,FY,FZ); EXPV(A,4,1,FX,FY,FZ); }

__global__ __launch_bounds__(128, 1)
void qsim_kernel(const float* __restrict__ sv,      // [B, 4096]
                 const float* __restrict__ cf,      // [320] precomputed coefficients
                 const float* __restrict__ W,       // [10, 36]
                 const float* __restrict__ bvec,    // [10]
                 float* __restrict__ out)           // [B, 10]
{
    __shared__ F2 psi[DIM];          // 32 KB, shared by both states (alternating)
    const int t = threadIdx.x;
    const int b0 = blockIdx.x * 2;
    const int lane = t & 63, w = t >> 6;

    F2 amp1[32], amp2[32];
    const float* svb = sv + (size_t)b0 * DIM;
#pragma unroll
    for (int r = 0; r < 32; ++r) amp1[r] = make_float2(svb[(r << 7) | t], 0.f);
#pragma unroll
    for (int r = 0; r < 32; ++r) amp2[r] = make_float2(svb[DIM + ((r << 7) | t)], 0.f);

    float fx1 = 0.f, fy1 = 0.f, fz1 = 0.f;
    float fx2 = 0.f, fy2 = 0.f, fz2 = 0.f;

    // ---- phase A on state1; pipeline start ----
    GA(amp1);
    ST(amp1, addrA, swzAB);          // T1: A->B, state1
    GA(amp2);                        //   hides st1 drain
    __syncthreads();
    LDR(amp1, addrB, swzAB);
    GB_1(amp1);                      //   hides ld1
    __syncthreads();                 //   buffer free
    ST(amp2, addrA, swzAB);          // T1: state2
    GB_2(amp1);                      //   hides st2
    __syncthreads();
    LDR(amp2, addrB, swzAB);
    GB_1(amp2);                      //   hides ld2
    __syncthreads();                 //   buffer free

    ST(amp1, addrB, swzBC);          // T2: B->C, state1
    GB_2(amp2);                      //   hides st1
    __syncthreads();
    LDR(amp1, addrC, swzBC);
    GC_1(amp1);
    __syncthreads();
    ST(amp2, addrB, swzBC);          // T2: state2
    GC_2(amp1, fx1, fy1, fz1);
    __syncthreads();
    LDR(amp2, addrC, swzBC);
    GC_1(amp2);
    __syncthreads();

    ST(amp1, addrC, swzBC);          // T3: C->B, state1
    GC_2(amp2, fx2, fy2, fz2);
    __syncthreads();
    LDR(amp1, addrB, swzBC);
    GBP_1(amp1);
    __syncthreads();
    ST(amp2, addrC, swzBC);          // T3: state2
    GBP_2(amp1, fx1, fy1, fz1);
    __syncthreads();
    LDR(amp2, addrB, swzBC);
    GBP_1(amp2);
    __syncthreads();

    ST(amp1, addrB, swzAB);          // T4: B->A, state1
    GBP_2(amp2, fx2, fy2, fz2);
    __syncthreads();
    LDR(amp1, addrA, swzAB);
    GAP_1(amp1);
    __syncthreads();
    ST(amp2, addrB, swzAB);          // T4: state2
    GAP_2(amp1, fx1, fy1, fz1);
    __syncthreads();
    LDR(amp2, addrA, swzAB);
    GAP_1(amp2); GAP_2(amp2, fx2, fy2, fz2);
    __syncthreads();                 // psi free -> feature buffer

    // ---- combine features: zones [state][wave][36] ----
    float* fbuf = (float*)psi;       // [4][36]
    if (lane < 12) {
        fbuf[w*36 + lane]            = fx1;
        fbuf[w*36 + 12 + lane]       = fy1;
        fbuf[w*36 + 24 + lane]       = fz1;
        fbuf[(2+w)*36 + lane]        = fx2;
        fbuf[(2+w)*36 + 12 + lane]   = fy2;
        fbuf[(2+w)*36 + 24 + lane]   = fz2;
    }
    __syncthreads();
    if (t < 10) {
        float a = bvec[t];
#pragma unroll
        for (int f = 0; f < 36; ++f)
            a += W[t*36 + f] * (fbuf[f] + fbuf[36 + f]);
        out[(size_t)b0*10 + t] = a;
    } else if (t >= 64 && t < 74) {
        int c = t - 64;
        float a = bvec[c];
#pragma unroll
        for (int f = 0; f < 36; ++f)
            a += W[c*36 + f] * (fbuf[72 + f] + fbuf[108 + f]);
        out[(size_t)(b0 + 1)*10 + c] = a;
    }
}

extern "C" void kernel_launch(void* const* d_in, const int* in_sizes, int n_in,
                              void* d_out, int out_size, void* d_ws, size_t ws_size,
                              hipStream_t stream) {
    const float* sv     = (const float*)d_in[0];
    const float* angles = (const float*)d_in[1];
    const float* W      = (const float*)d_in[2];
    const float* bvec   = (const float*)d_in[3];
    float* out  = (float*)d_out;
    float* coef = (float*)d_ws;      // 320 floats of scratch
    int batch = in_sizes[0] / DIM;   // 2048
    prep_kernel<<<1, 64, 0, stream>>>(angles, coef);
    qsim_kernel<<<batch / 2, 128, 0, stream>>>(sv, coef, W, bvec, out);
}

// Round 12
// 147.150 us; speedup vs baseline: 1.1974x; 1.1974x over previous
//
#include <hip/hip_runtime.h>

#define DIM 4096
using F2 = float2;

// R12 = R7/R8 structure (256 thr/block, 16 amps/thread, 7 phases, 6 transposes;
// best waves/SIMD) + R9's L0-ring fusion (CR0(q-1,q) folded into U0(q) via
// compile-time matrix select; CR0(11,0) folded into U1(0)). pk fp32 math (R8).
// Qubit q lives at amplitude bit (11-q).
// Layout A/H: quad {0,1,2,3}  masks {8,4,2,1}
// Layout B/G: quad {3,4,5,6}  masks {8,4,2,1}
// Layout C/F: quad {6,7,8,9}  masks {8,4,2,1}
// Layout DE : quad {9,10,11,0} masks {q0=8, q9=4, q10=2, q11=1}

__device__ __forceinline__ int swz(int i)          { return i ^ (i >> 6); }
__device__ __forceinline__ int addrA(int r, int t) { return (r << 8) | t; }
__device__ __forceinline__ int addrB(int r, int t) { return ((t >> 5) << 9) | (r << 5) | (t & 31); }
__device__ __forceinline__ int addrC(int r, int t) { return ((t >> 2) << 6) | (r << 2) | (t & 3); }
__device__ __forceinline__ int addrD(int r, int t) { return ((r >> 3) << 11) | (t << 3) | (r & 7); }

// ---- packed fp32 complex primitives (VOP3P) — proven R8-R11 ----
__device__ __forceinline__ F2 pk_mul_bl(F2 a, F2 u) {   // (a.x*u.x, a.y*u.x)
    F2 d;
    asm("v_pk_mul_f32 %0, %1, %2 op_sel:[0,0] op_sel_hi:[1,0]"
        : "=v"(d) : "v"(a), "v"(u));
    return d;
}
__device__ __forceinline__ void pk_cross(F2& d, F2 a, F2 u) {  // d += (-a.y*u.y, a.x*u.y)
    asm("v_pk_fma_f32 %0, %1, %2, %0 op_sel:[1,1,0] op_sel_hi:[0,1,1] neg_lo:[1,0,0]"
        : "+v"(d) : "v"(a), "v"(u));
}
__device__ __forceinline__ void pk_fma_bl(F2& d, F2 a, F2 u) { // d += (a.x*u.x, a.y*u.x)
    asm("v_pk_fma_f32 %0, %1, %2, %0 op_sel:[0,0,0] op_sel_hi:[1,0,1]"
        : "+v"(d) : "v"(a), "v"(u));
}
__device__ __forceinline__ void pk_swapneg(F2& d, F2 a, F2 cs) { // d += (a.y*cs.y, -a.x*cs.y)
    asm("v_pk_fma_f32 %0, %1, %2, %0 op_sel:[1,1,0] op_sel_hi:[0,1,1] neg_hi:[1,0,0]"
        : "+v"(d) : "v"(a), "v"(cs));
}
__device__ __forceinline__ void pk_fma(F2& d, F2 a, F2 b) {    // d += a*b
    asm("v_pk_fma_f32 %0, %1, %2, %0" : "+v"(d) : "v"(a), "v"(b));
}
__device__ __forceinline__ void pk_imacc(F2& d, F2 a0, F2 a1) { // d += (a0.x*a1.y, -a0.y*a1.x)
    asm("v_pk_fma_f32 %0, %1, %2, %0 op_sel:[0,1,0] op_sel_hi:[1,0,1] neg_hi:[1,0,0]"
        : "+v"(d) : "v"(a0), "v"(a1));
}
__device__ __forceinline__ F2 pk_cmul(F2 u, F2 a) {
    F2 d = pk_mul_bl(a, u);
    pk_cross(d, a, u);
    return d;
}
__device__ __forceinline__ void pk_cfma(F2& d, F2 u, F2 a) {
    pk_fma_bl(d, a, u);
    pk_cross(d, a, u);
}

__device__ __forceinline__ void build_u(float tx, float ty, float tz, float* u) {
    float sx = sinf(0.5f*tx), cx = cosf(0.5f*tx);
    float sy = sinf(0.5f*ty), cy = cosf(0.5f*ty);
    float sz = sinf(0.5f*tz), cz = cosf(0.5f*tz);
    float A00r = cy*cx, A00i =  sy*sx;     // A = Ry*Rx
    float A01r = -sy*cx, A01i = -cy*sx;
    float A10r =  sy*cx, A10i = -cy*sx;
    float A11r =  cy*cx, A11i = -sy*sx;
    // U = Rz*A: row0 *= (cz - i sz), row1 *= (cz + i sz)   [verified r1/3/5..11]
    u[0] = cz*A00r + sz*A00i;  u[1] = cz*A00i - sz*A00r;
    u[2] = cz*A01r + sz*A01i;  u[3] = cz*A01i - sz*A01r;
    u[4] = cz*A10r - sz*A10i;  u[5] = cz*A10i + sz*A10r;
    u[6] = cz*A11r - sz*A11i;  u[7] = cz*A11i + sz*A11r;
}

// coef layout (floats): [0..95] U0 plain (q*8); [96..191] RX(ang[36+q-1])*U0[q] (q=1..11);
// [192..287] U1 plain; [288..295] U1[0]*RX(ang[47]); [296..319] L1 CRX (cos,sin)[ctrl c]
__global__ void prep_kernel(const float* __restrict__ ang, float* __restrict__ coef) {
    int t = threadIdx.x;
    if (t < 12) {
        float u[8]; build_u(ang[t], ang[12+t], ang[24+t], u);
#pragma unroll
        for (int j = 0; j < 8; ++j) coef[t*8 + j] = u[j];
    } else if (t < 24) {
        int q = t - 12;
        float u[8]; build_u(ang[48+q], ang[60+q], ang[72+q], u);
#pragma unroll
        for (int j = 0; j < 8; ++j) coef[192 + q*8 + j] = u[j];
    } else if (t < 36) {
        int c = t - 24;
        float th = 0.5f * ang[95 - c];     // L1 ring gate (c,c+1) = tape slot 84+(11-c)
        coef[296 + c*2]     = cosf(th);
        coef[296 + c*2 + 1] = sinf(th);
    } else if (t < 47) {
        int q = t - 35;                    // 1..11: M = RX(ang[36+q-1]) * U0[q]
        float u[8]; build_u(ang[q], ang[12+q], ang[24+q], u);
        float c = cosf(0.5f*ang[36+q-1]), s = sinf(0.5f*ang[36+q-1]);
        float m[8];
        m[0] = c*u[0] + s*u[5];  m[1] = c*u[1] - s*u[4];   // M00 = c u00 - i s u10
        m[2] = c*u[2] + s*u[7];  m[3] = c*u[3] - s*u[6];   // M01 = c u01 - i s u11
        m[4] = s*u[1] + c*u[4];  m[5] = -s*u[0] + c*u[5];  // M10 = -i s u00 + c u10
        m[6] = s*u[3] + c*u[6];  m[7] = -s*u[2] + c*u[7];  // M11 = -i s u01 + c u11
#pragma unroll
        for (int j = 0; j < 8; ++j) coef[96 + q*8 + j] = m[j];
    } else if (t == 47) {                  // M = U1[0] * RX(ang[47])  [CR0(11,0) then U1(0)]
        float u[8]; build_u(ang[48], ang[60], ang[72], u);
        float c = cosf(0.5f*ang[47]), s = sinf(0.5f*ang[47]);
        float m[8];
        m[0] = c*u[0] + s*u[3];  m[1] = c*u[1] - s*u[2];   // M00 = c u00 - i s u01
        m[2] = s*u[1] + c*u[2];  m[3] = -s*u[0] + c*u[3];  // M01 = -i s u00 + c u01
        m[4] = c*u[4] + s*u[7];  m[5] = c*u[5] - s*u[6];   // M10 = c u10 - i s u11
        m[6] = s*u[5] + c*u[6];  m[7] = -s*u[4] + c*u[7];  // M11 = -i s u10 + c u11
#pragma unroll
        for (int j = 0; j < 8; ++j) coef[288 + j] = m[j];
    }
}

template<int M>  // plain fused-1q on reg-bit M pairs (8 pairs over 16 slots)
__device__ __forceinline__ void g1q(F2* amp, const float* __restrict__ u) {
    F2 u00 = {u[0], u[1]}, u01 = {u[2], u[3]};
    F2 u10 = {u[4], u[5]}, u11 = {u[6], u[7]};
#pragma unroll
    for (int r0 = 0; r0 < 16; ++r0) {
        if (r0 & M) continue;
        const int r1 = r0 + M;
        F2 a0 = amp[r0], a1 = amp[r1];
        F2 n0 = pk_cmul(u00, a0); pk_cfma(n0, u01, a1);
        F2 n1 = pk_cmul(u10, a0); pk_cfma(n1, u11, a1);
        amp[r0] = n0; amp[r1] = n1;
    }
}

template<int MSEL, int M>   // matrix selected by compile-time control reg bit MSEL
__device__ __forceinline__ void fg1q(F2* amp, const float* __restrict__ uA,
                                     const float* __restrict__ uB) {
    F2 a00 = {uA[0], uA[1]}, a01 = {uA[2], uA[3]}, a10 = {uA[4], uA[5]}, a11 = {uA[6], uA[7]};
    F2 b00 = {uB[0], uB[1]}, b01 = {uB[2], uB[3]}, b10 = {uB[4], uB[5]}, b11 = {uB[6], uB[7]};
#pragma unroll
    for (int r0 = 0; r0 < 16; ++r0) {
        if (r0 & M) continue;
        const int r1 = r0 + M;
        const bool sel = (r0 & MSEL) != 0;           // compile-time
        F2 u00 = sel ? b00 : a00, u01 = sel ? b01 : a01;
        F2 u10 = sel ? b10 : a10, u11 = sel ? b11 : a11;
        F2 a0 = amp[r0], a1 = amp[r1];
        F2 n0 = pk_cmul(u00, a0); pk_cfma(n0, u01, a1);
        F2 n1 = pk_cmul(u10, a0); pk_cfma(n1, u11, a1);
        amp[r0] = n0; amp[r1] = n1;
    }
}

template<int MC, int MT>  // plain CRX (4 pairs over 16 slots)
__device__ __forceinline__ void crx(F2* amp, F2 cs) {
#pragma unroll
    for (int r0 = 0; r0 < 16; ++r0) {
        if (!(r0 & MC) || (r0 & MT)) continue;
        const int r1 = r0 + MT;
        F2 a0 = amp[r0], a1 = amp[r1];
        F2 n0 = pk_mul_bl(a0, cs); pk_swapneg(n0, a1, cs);
        F2 n1 = pk_mul_bl(a1, cs); pk_swapneg(n1, a0, cs);
        amp[r0] = n0; amp[r1] = n1;
    }
}

template<int M>  // wave-reduce <X_q>,<Y_q>,<Z_q>; park totals in lane q
__device__ __forceinline__ void expv(const F2* amp, int q, int lane,
                                     float& fx, float& fy, float& fz) {
    F2 zp = {0.f, 0.f}, zm = {0.f, 0.f}, xp = {0.f, 0.f}, ip = {0.f, 0.f};
#pragma unroll
    for (int r0 = 0; r0 < 16; ++r0) {
        if (r0 & M) continue;
        const int r1 = r0 + M;
        F2 a0 = amp[r0], a1 = amp[r1];
        pk_fma(zp, a0, a0);
        pk_fma(zm, a1, a1);
        pk_fma(xp, a0, a1);
        pk_imacc(ip, a0, a1);
    }
    float zz = (zp.x + zp.y) - (zm.x + zm.y);
    float xr = 2.f * (xp.x + xp.y);
    float xi = 2.f * (ip.x + ip.y);
#pragma unroll
    for (int off = 32; off; off >>= 1) {
        xr += __shfl_xor(xr, off);
        xi += __shfl_xor(xi, off);
        zz += __shfl_xor(zz, off);
    }
    if (lane == q) { fx = xr; fy = xi; fz = zz; }
}

#define XPOSE(CUR, NXT) \
  { _Pragma("unroll") for (int r = 0; r < 16; ++r) psi[swz(CUR(r, t))] = amp[r]; \
    __syncthreads(); \
    _Pragma("unroll") for (int r = 0; r < 16; ++r) amp[r] = psi[swz(NXT(r, t))]; \
    __syncthreads(); }

#define U0P(q, M)       g1q<M>(amp, cf + (q)*8)
#define FU0(q, MS, M)   fg1q<MS, M>(amp, cf + (q)*8, cf + 96 + (q)*8)
#define U1P(q, M)       g1q<M>(amp, cf + 192 + (q)*8)
#define CR1(c, MC, MT)  crx<MC, MT>(amp, F2{cf[296 + (c)*2], cf[296 + (c)*2 + 1]})
#define EXPV(q, M)      expv<M>(amp, q, lane, fx, fy, fz)

// R12: back to 256-thr structure (R7/R8, best waves/SIMD) + R9 fusion.
__global__ __launch_bounds__(256, 1)
void qsim_kernel(const float* __restrict__ sv,      // [B, 4096]
                 const float* __restrict__ cf,      // [320] precomputed coefficients
                 const float* __restrict__ W,       // [10, 36]
                 const float* __restrict__ bvec,    // [10]
                 float* __restrict__ out)           // [B, 10]
{
    __shared__ F2 psi[DIM];          // exactly 32 KB -> 5 blocks/CU LDS ceiling
    const int t = threadIdx.x;
    const int b = blockIdx.x;
    const int lane = t & 63, w = t >> 6;

    F2 amp[16];
    const float* svb = sv + (size_t)b * DIM;
#pragma unroll
    for (int r = 0; r < 16; ++r)                    // layout A, coalesced
        amp[r] = make_float2(svb[(r << 8) | t], 0.f);

    float fx = 0.f, fy = 0.f, fz = 0.f;

    // ---- A {0,1,2,3}: U0(0); [U0(q);CR0(q-1,q)] q=1..3 ----
    U0P(0, 8);
    FU0(1, 8, 4); FU0(2, 4, 2); FU0(3, 2, 1);
    XPOSE(addrA, addrB);

    // ---- B {3,4,5,6}: [U0(q);CR0(q-1,q)] q=4..6 ----
    FU0(4, 8, 4); FU0(5, 4, 2); FU0(6, 2, 1);
    XPOSE(addrB, addrC);

    // ---- C {6,7,8,9}: [U0(q);CR0(q-1,q)] q=7..9 ----
    FU0(7, 8, 4); FU0(8, 4, 2); FU0(9, 2, 1);
    XPOSE(addrC, addrD);

    // ---- DE {q0=8,q9=4,q10=2,q11=1}: [U0;CR0] q=10,11; [CR0(11,0);U1(0)];
    //      U1(9,10,11); L1 ring (11,0),(10,11),(9,10); expv 10,11 ----
    FU0(10, 4, 2); FU0(11, 2, 1);
    fg1q<1, 8>(amp, cf + 192, cf + 288);   // ctrl q11(1) -> U1(0) or U1(0)*RX, on q0(8)
    U1P(9, 4); U1P(10, 2); U1P(11, 1);
    CR1(11, 1, 8); CR1(10, 2, 1); CR1(9, 4, 2);
    EXPV(10, 2); EXPV(11, 1);
    XPOSE(addrD, addrC);

    // ---- F {6,7,8,9}: U1(6,7,8); L1 ring (8,9),(7,8),(6,7); expv 7,8,9 ----
    U1P(6, 8); U1P(7, 4); U1P(8, 2);
    CR1(8, 2, 1); CR1(7, 4, 2); CR1(6, 8, 4);
    EXPV(9, 1); EXPV(8, 2); EXPV(7, 4);
    XPOSE(addrC, addrB);

    // ---- G {3,4,5,6}: U1(3,4,5); L1 ring (5,6),(4,5),(3,4); expv 4,5,6 ----
    U1P(3, 8); U1P(4, 4); U1P(5, 2);
    CR1(5, 2, 1); CR1(4, 4, 2); CR1(3, 8, 4);
    EXPV(6, 1); EXPV(5, 2); EXPV(4, 4);
    XPOSE(addrB, addrA);

    // ---- H {0,1,2,3}: U1(1,2); L1 ring (2,3),(1,2),(0,1); expv 0..3 ----
    U1P(1, 4); U1P(2, 2);
    CR1(2, 2, 1); CR1(1, 4, 2); CR1(0, 8, 4);
    EXPV(0, 8); EXPV(1, 4); EXPV(2, 2); EXPV(3, 1);
    __syncthreads();                 // psi free -> feature buffer

    // ---- combine 4 waves' features (psi dead: alias), head, store ----
    float* fbuf = (float*)psi;       // [4][36]
    if (lane < 12) {
        fbuf[w * 36 + lane]      = fx;
        fbuf[w * 36 + 12 + lane] = fy;
        fbuf[w * 36 + 24 + lane] = fz;
    }
    __syncthreads();
    if (t < 10) {
        float a = bvec[t];
#pragma unroll
        for (int f = 0; f < 36; ++f)
            a += W[t * 36 + f] * (fbuf[f] + fbuf[36 + f] + fbuf[72 + f] + fbuf[108 + f]);
        out[(size_t)b * 10 + t] = a;
    }
}

extern "C" void kernel_launch(void* const* d_in, const int* in_sizes, int n_in,
                              void* d_out, int out_size, void* d_ws, size_t ws_size,
                              hipStream_t stream) {
    const float* sv     = (const float*)d_in[0];
    const float* angles = (const float*)d_in[1];
    const float* W      = (const float*)d_in[2];
    const float* bvec   = (const float*)d_in[3];
    float* out  = (float*)d_out;
    float* coef = (float*)d_ws;      // 320 floats of scratch
    int batch = in_sizes[0] / DIM;   // 2048
    prep_kernel<<<1, 64, 0, stream>>>(angles, coef);
    qsim_kernel<<<batch, 256, 0, stream>>>(sv, coef, W, bvec, out);
}

// Round 13
// 134.593 us; speedup vs baseline: 1.3091x; 1.0933x over previous
//
#include <hip/hip_runtime.h>

#define DIM 4096
using F2 = float2;

// R13 = R9 (champion: 70 µs rocprof) with two stall-only reorderings:
//  (1) phase C / B' EXPV work moved between ST and barrier (fills store drain;
//      EXPV reads amp regs only — independent of LDS stores),
//  (2) post-barrier reloads issued in the first gate's pair order so the
//      compiler's fine-grained lgkmcnt lets gate 1 start after 2 loads.
// Gate schedule, layouts, swizzles, math: byte-identical to R9.
// Layout A: reg = a[11:7], qubits {0,1,2,3,4} masks {16,8,4,2,1}; t = a[6:0]
// Layout B: reg = a[7:3],  qubits {4,5,6,7,8} masks {16,8,4,2,1}; t = {a[11:8],a[2:0]}
// Layout C: reg = {a[3:0],a[11]}, qubits {8,9,10,11,0} masks {16,8,4,2,1}; t = a[10:4]

__device__ __forceinline__ int addrA(int r, int t) { return (r << 7) | t; }
__device__ __forceinline__ int addrB(int r, int t) { return ((t >> 3) << 8) | (r << 3) | (t & 7); }
__device__ __forceinline__ int addrC(int r, int t) { return ((r & 1) << 11) | (t << 4) | (r >> 1); }
__device__ __forceinline__ int swzAB(int a) { return a ^ ((a >> 5) & 8); }
__device__ __forceinline__ int swzBC(int a) { return a ^ ((a >> 4) & 15) ^ ((a >> 5) & 8); }

// ---- packed fp32 complex primitives (VOP3P) — proven R8-R12 ----
__device__ __forceinline__ F2 pk_mul_bl(F2 a, F2 u) {   // (a.x*u.x, a.y*u.x)
    F2 d;
    asm("v_pk_mul_f32 %0, %1, %2 op_sel:[0,0] op_sel_hi:[1,0]"
        : "=v"(d) : "v"(a), "v"(u));
    return d;
}
__device__ __forceinline__ void pk_cross(F2& d, F2 a, F2 u) {  // d += (-a.y*u.y, a.x*u.y)
    asm("v_pk_fma_f32 %0, %1, %2, %0 op_sel:[1,1,0] op_sel_hi:[0,1,1] neg_lo:[1,0,0]"
        : "+v"(d) : "v"(a), "v"(u));
}
__device__ __forceinline__ void pk_fma_bl(F2& d, F2 a, F2 u) { // d += (a.x*u.x, a.y*u.x)
    asm("v_pk_fma_f32 %0, %1, %2, %0 op_sel:[0,0,0] op_sel_hi:[1,0,1]"
        : "+v"(d) : "v"(a), "v"(u));
}
__device__ __forceinline__ void pk_swapneg(F2& d, F2 a, F2 cs) { // d += (a.y*cs.y, -a.x*cs.y)
    asm("v_pk_fma_f32 %0, %1, %2, %0 op_sel:[1,1,0] op_sel_hi:[0,1,1] neg_hi:[1,0,0]"
        : "+v"(d) : "v"(a), "v"(cs));
}
__device__ __forceinline__ void pk_fma(F2& d, F2 a, F2 b) {    // d += a*b
    asm("v_pk_fma_f32 %0, %1, %2, %0" : "+v"(d) : "v"(a), "v"(b));
}
__device__ __forceinline__ void pk_imacc(F2& d, F2 a0, F2 a1) { // d += (a0.x*a1.y, -a0.y*a1.x)
    asm("v_pk_fma_f32 %0, %1, %2, %0 op_sel:[0,1,0] op_sel_hi:[1,0,1] neg_hi:[1,0,0]"
        : "+v"(d) : "v"(a0), "v"(a1));
}
__device__ __forceinline__ F2 pk_cmul(F2 u, F2 a) {
    F2 d = pk_mul_bl(a, u);
    pk_cross(d, a, u);
    return d;
}
__device__ __forceinline__ void pk_cfma(F2& d, F2 u, F2 a) {
    pk_fma_bl(d, a, u);
    pk_cross(d, a, u);
}

__device__ __forceinline__ void build_u(float tx, float ty, float tz, float* u) {
    float sx = sinf(0.5f*tx), cx = cosf(0.5f*tx);
    float sy = sinf(0.5f*ty), cy = cosf(0.5f*ty);
    float sz = sinf(0.5f*tz), cz = cosf(0.5f*tz);
    float A00r = cy*cx, A00i =  sy*sx;     // A = Ry*Rx
    float A01r = -sy*cx, A01i = -cy*sx;
    float A10r =  sy*cx, A10i = -cy*sx;
    float A11r =  cy*cx, A11i = -sy*sx;
    // U = Rz*A: row0 *= (cz - i sz), row1 *= (cz + i sz)   [verified r1/3/5..12]
    u[0] = cz*A00r + sz*A00i;  u[1] = cz*A00i - sz*A00r;
    u[2] = cz*A01r + sz*A01i;  u[3] = cz*A01i - sz*A01r;
    u[4] = cz*A10r - sz*A10i;  u[5] = cz*A10i + sz*A10r;
    u[6] = cz*A11r - sz*A11i;  u[7] = cz*A11i + sz*A11r;
}

// coef layout (floats): [0..95] U0 plain (q*8); [96..191] RX(ang[36+q-1])*U0[q] (q=1..11);
// [192..287] U1 plain; [288..295] U1[0]*RX(ang[47]); [296..319] L1 CRX (cos,sin)[c=0..11]
__global__ void prep_kernel(const float* __restrict__ ang, float* __restrict__ coef) {
    int t = threadIdx.x;
    if (t < 12) {
        float u[8]; build_u(ang[t], ang[12+t], ang[24+t], u);
#pragma unroll
        for (int j = 0; j < 8; ++j) coef[t*8 + j] = u[j];
    } else if (t < 24) {
        int q = t - 12;
        float u[8]; build_u(ang[48+q], ang[60+q], ang[72+q], u);
#pragma unroll
        for (int j = 0; j < 8; ++j) coef[192 + q*8 + j] = u[j];
    } else if (t < 36) {
        int c = t - 24;
        float th = 0.5f * ang[95 - c];     // L1 ring gate (c,c+1) = tape slot 84+(11-c)
        coef[296 + c*2]     = cosf(th);
        coef[296 + c*2 + 1] = sinf(th);
    } else if (t < 47) {
        int q = t - 35;                    // 1..11: M = RX(ang[36+q-1]) * U0[q]
        float u[8]; build_u(ang[q], ang[12+q], ang[24+q], u);
        float c = cosf(0.5f*ang[36+q-1]), s = sinf(0.5f*ang[36+q-1]);
        float m[8];
        m[0] = c*u[0] + s*u[5];  m[1] = c*u[1] - s*u[4];   // M00 = c u00 - i s u10
        m[2] = c*u[2] + s*u[7];  m[3] = c*u[3] - s*u[6];   // M01 = c u01 - i s u11
        m[4] = s*u[1] + c*u[4];  m[5] = -s*u[0] + c*u[5];  // M10 = -i s u00 + c u10
        m[6] = s*u[3] + c*u[6];  m[7] = -s*u[2] + c*u[7];  // M11 = -i s u01 + c u11
#pragma unroll
        for (int j = 0; j < 8; ++j) coef[96 + q*8 + j] = m[j];
    } else if (t == 47) {                  // M = U1[0] * RX(ang[47])  [CR0(11,0) then U1(0)]
        float u[8]; build_u(ang[48], ang[60], ang[72], u);
        float c = cosf(0.5f*ang[47]), s = sinf(0.5f*ang[47]);
        float m[8];
        m[0] = c*u[0] + s*u[3];  m[1] = c*u[1] - s*u[2];   // M00 = c u00 - i s u01
        m[2] = s*u[1] + c*u[2];  m[3] = -s*u[0] + c*u[3];  // M01 = -i s u00 + c u01
        m[4] = c*u[4] + s*u[7];  m[5] = c*u[5] - s*u[6];   // M10 = c u10 - i s u11
        m[6] = s*u[5] + c*u[6];  m[7] = -s*u[4] + c*u[7];  // M11 = -i s u10 + c u11
#pragma unroll
        for (int j = 0; j < 8; ++j) coef[288 + j] = m[j];
    }
}

template<int M>
__device__ __forceinline__ void g1q(F2* amp, const float* __restrict__ u) {
    F2 u00 = {u[0], u[1]}, u01 = {u[2], u[3]};
    F2 u10 = {u[4], u[5]}, u11 = {u[6], u[7]};
#pragma unroll
    for (int r0 = 0; r0 < 32; ++r0) {
        if (r0 & M) continue;
        const int r1 = r0 + M;
        F2 a0 = amp[r0], a1 = amp[r1];
        F2 n0 = pk_cmul(u00, a0); pk_cfma(n0, u01, a1);
        F2 n1 = pk_cmul(u10, a0); pk_cfma(n1, u11, a1);
        amp[r0] = n0; amp[r1] = n1;
    }
}

template<int MSEL, int M>   // matrix selected by compile-time control reg bit MSEL
__device__ __forceinline__ void fg1q(F2* amp, const float* __restrict__ uA,
                                     const float* __restrict__ uB) {
    F2 a00 = {uA[0], uA[1]}, a01 = {uA[2], uA[3]}, a10 = {uA[4], uA[5]}, a11 = {uA[6], uA[7]};
    F2 b00 = {uB[0], uB[1]}, b01 = {uB[2], uB[3]}, b10 = {uB[4], uB[5]}, b11 = {uB[6], uB[7]};
#pragma unroll
    for (int r0 = 0; r0 < 32; ++r0) {
        if (r0 & M) continue;
        const int r1 = r0 + M;
        const bool sel = (r0 & MSEL) != 0;           // compile-time
        F2 u00 = sel ? b00 : a00, u01 = sel ? b01 : a01;
        F2 u10 = sel ? b10 : a10, u11 = sel ? b11 : a11;
        F2 a0 = amp[r0], a1 = amp[r1];
        F2 n0 = pk_cmul(u00, a0); pk_cfma(n0, u01, a1);
        F2 n1 = pk_cmul(u10, a0); pk_cfma(n1, u11, a1);
        amp[r0] = n0; amp[r1] = n1;
    }
}

template<int MC, int MT>
__device__ __forceinline__ void crx(F2* amp, F2 cs) {
#pragma unroll
    for (int r0 = 0; r0 < 32; ++r0) {
        if (!(r0 & MC) || (r0 & MT)) continue;
        const int r1 = r0 + MT;
        F2 a0 = amp[r0], a1 = amp[r1];
        F2 n0 = pk_mul_bl(a0, cs); pk_swapneg(n0, a1, cs);
        F2 n1 = pk_mul_bl(a1, cs); pk_swapneg(n1, a0, cs);
        amp[r0] = n0; amp[r1] = n1;
    }
}

template<int M>
__device__ __forceinline__ void expv(const F2* amp, int q, int lane,
                                     float& fx, float& fy, float& fz) {
    F2 zp = {0.f, 0.f}, zm = {0.f, 0.f}, xp = {0.f, 0.f}, ip = {0.f, 0.f};
#pragma unroll
    for (int r0 = 0; r0 < 32; ++r0) {
        if (r0 & M) continue;
        const int r1 = r0 + M;
        F2 a0 = amp[r0], a1 = amp[r1];
        pk_fma(zp, a0, a0);
        pk_fma(zm, a1, a1);
        pk_fma(xp, a0, a1);
        pk_imacc(ip, a0, a1);
    }
    float zz = (zp.x + zp.y) - (zm.x + zm.y);
    float xr = 2.f * (xp.x + xp.y);
    float xi = 2.f * (ip.x + ip.y);
#pragma unroll
    for (int off = 32; off; off >>= 1) {
        xr += __shfl_xor(xr, off);
        xi += __shfl_xor(xi, off);
        zz += __shfl_xor(zz, off);
    }
    if (lane == q) { fx = xr; fy = xi; fz = zz; }
}

// Store all 32 regs (order irrelevant for drain).
#define ST(ADDR, SWZ) \
  { _Pragma("unroll") for (int r = 0; r < 32; ++r) psi[SWZ(ADDR(r, t))] = amp[r]; }
// Load all 32 regs in pair order of the next phase's first gate (mask M):
// pairs (r0, r0+M) issue adjacently so the first gate starts after 2 loads.
#define LDP(ADDR, SWZ, M) \
  { _Pragma("unroll") for (int k = 0; k < 32; ++k) { \
      const int j = k >> 1; \
      const int r0 = ((j & ~((M) - 1)) << 1) | (j & ((M) - 1)); \
      const int r = (k & 1) ? (r0 + (M)) : r0; \
      amp[r] = psi[SWZ(ADDR(r, t))]; } }

#define U0P(q, M)       g1q<M>(amp, cf + (q)*8)
#define FU0(q, MS, M)   fg1q<MS, M>(amp, cf + (q)*8, cf + 96 + (q)*8)
#define U1P(q, M)       g1q<M>(amp, cf + 192 + (q)*8)
#define FU1_0()         fg1q<2, 1>(amp, cf + 192, cf + 288)
#define CR1(c, MC, MT)  crx<MC, MT>(amp, F2{cf[296 + (c)*2], cf[296 + (c)*2 + 1]})
#define EXPV(q, M)      expv<M>(amp, q, lane, fx, fy, fz)

__global__ __launch_bounds__(128, 1)
void qsim_kernel(const float* __restrict__ sv,      // [B, 4096]
                 const float* __restrict__ cf,      // [320] precomputed coefficients
                 const float* __restrict__ W,       // [10, 36]
                 const float* __restrict__ bvec,    // [10]
                 float* __restrict__ out)           // [B, 10]
{
    __shared__ F2 psi[DIM];          // exactly 32 KB
    const int t = threadIdx.x;
    const int b = blockIdx.x;
    const int lane = t & 63, w = t >> 6;

    F2 amp[32];
    const float* svb = sv + (size_t)b * DIM;
#pragma unroll
    for (int r = 0; r < 32; ++r)                    // layout A, coalesced
        amp[r] = make_float2(svb[(r << 7) | t], 0.f);

    float fx = 0.f, fy = 0.f, fz = 0.f;

    // ---- A {0,1,2,3,4}: U0(0); [U0(q);CR0(q-1,q)] q=1..4 ----
    U0P(0, 16);
    FU0(1, 16, 8); FU0(2, 8, 4); FU0(3, 4, 2); FU0(4, 2, 1);
    ST(addrA, swzAB);
    __syncthreads();
    LDP(addrB, swzAB, 8);            // first B gate: FU0(5,16,8) -> pairs on mask 8
    __syncthreads();

    // ---- B {4,5,6,7,8}: [U0(q);CR0(q-1,q)] q=5..8 ----
    FU0(5, 16, 8); FU0(6, 8, 4); FU0(7, 4, 2); FU0(8, 2, 1);
    ST(addrB, swzBC);
    __syncthreads();
    LDP(addrC, swzBC, 8);            // first C gate: FU0(9,16,8)
    __syncthreads();

    // ---- C {8,9,10,11,0}: [U0(q);CR0(q-1,q)] q=9..11; [CR0(11,0);U1(0)];
    //      U1(8..11); L1 ring (11,0),(10,11),(9,10),(8,9); expv 9,10,11 ----
    FU0(9, 16, 8); FU0(10, 8, 4); FU0(11, 4, 2);
    FU1_0();
    U1P(8, 16); U1P(9, 8); U1P(10, 4); U1P(11, 2);
    CR1(11, 2, 1); CR1(10, 4, 2); CR1(9, 8, 4); CR1(8, 16, 8);
    ST(addrC, swzBC);
    EXPV(9, 8); EXPV(10, 4); EXPV(11, 2);    // reads amp only — fills store drain
    __syncthreads();
    LDP(addrB, swzBC, 16);           // first B' gate: U1P(4,16)
    __syncthreads();

    // ---- B' {4,5,6,7,8}: U1(4..7); L1 ring (7,8),(6,7),(5,6),(4,5); expv 5..8 ----
    U1P(4, 16); U1P(5, 8); U1P(6, 4); U1P(7, 2);
    CR1(7, 2, 1); CR1(6, 4, 2); CR1(5, 8, 4); CR1(4, 16, 8);
    ST(addrB, swzAB);
    EXPV(5, 8); EXPV(6, 4); EXPV(7, 2); EXPV(8, 1);   // fills store drain
    __syncthreads();
    LDP(addrA, swzAB, 8);            // first A' gate: U1P(1,8)
    __syncthreads();

    // ---- A' {0,1,2,3,4}: U1(1,2,3); L1 ring (3,4),(2,3),(1,2),(0,1); expv 0..4 ----
    U1P(1, 8); U1P(2, 4); U1P(3, 2);
    CR1(3, 2, 1); CR1(2, 4, 2); CR1(1, 8, 4); CR1(0, 16, 8);
    EXPV(0, 16); EXPV(1, 8); EXPV(2, 4); EXPV(3, 2); EXPV(4, 1);

    // ---- combine 2 waves' features (psi dead after last LDP+sync: alias) ----
    float* fbuf = (float*)psi;       // [2][36]
    if (lane < 12) {
        fbuf[w * 36 + lane]      = fx;
        fbuf[w * 36 + 12 + lane] = fy;
        fbuf[w * 36 + 24 + lane] = fz;
    }
    __syncthreads();
    if (t < 10) {
        float a = bvec[t];
#pragma unroll
        for (int f = 0; f < 36; ++f)
            a += W[t * 36 + f] * (fbuf[f] + fbuf[36 + f]);
        out[(size_t)b * 10 + t] = a;
    }
}

extern "C" void kernel_launch(void* const* d_in, const int* in_sizes, int n_in,
                              void* d_out, int out_size, void* d_ws, size_t ws_size,
                              hipStream_t stream) {
    const float* sv     = (const float*)d_in[0];
    const float* angles = (const float*)d_in[1];
    const float* W      = (const float*)d_in[2];
    const float* bvec   = (const float*)d_in[3];
    float* out  = (float*)d_out;
    float* coef = (float*)d_ws;      // 320 floats of scratch
    int batch = in_sizes[0] / DIM;   // 2048
    prep_kernel<<<1, 64, 0, stream>>>(angles, coef);
    qsim_kernel<<<batch, 128, 0, stream>>>(sv, coef, W, bvec, out);
}